// Round 3
// baseline (592.971 us; speedup 1.0000x reference)
//
#include <hip/hip_runtime.h>
#include <hip/hip_bf16.h>
#include <math.h>

// Problem constants (fixed by the reference)
#define N_NODES 100000
#define N_EDGES 1600000
#define NFEAT 128
#define NHID  64
#define NCLASS 40
#define NL 6

#define NBUK 256          // coarse buckets for CSR build
#define RPB  391          // rows per bucket (391*256 >= 100000)
#define EPP  (N_EDGES / NBUK)  // 6250 edges per partition block (exact)
#define EP_PAD 256        // zero-padded ep tail for pipelined spmm reads
#define NTILES (N_NODES / 16)  // 6250 row-tiles, exact

typedef __attribute__((ext_vector_type(8))) short short8;
typedef __attribute__((ext_vector_type(8))) unsigned short ushort8v;
typedef __attribute__((ext_vector_type(4))) float floatx4;
typedef __attribute__((ext_vector_type(2))) float float2v;

__device__ __forceinline__ float bfbits(unsigned short u) {
  return __uint_as_float((unsigned int)u << 16);
}
__device__ __forceinline__ short f2bs(float f) {
  __hip_bfloat16 h = __float2bfloat16(f);  // RNE
  return *reinterpret_cast<short*>(&h);
}

// Packed IEEE fma: acc = a*b + acc per 32-bit half. Bit-identical to 2x fmaf.
__device__ __forceinline__ void pkfma(float2v& acc, float2v a, float2v b) {
  asm("v_pk_fma_f32 %0, %1, %2, %0" : "+v"(acc) : "v"(a), "v"(b));
}

// 8 bf16 feats (as uint4 dwords, lo ushort = even feat) * scalar v -> 4 pk_fma.
// Per-j accumulation order identical to the scalar baseline (independent chains).
__device__ __forceinline__ void fma8pk(float2v& A01, float2v& A23, float2v& A45,
                                       float2v& A67, float v, uint4 g) {
  float2v vv; vv.x = v; vv.y = v;
  float2v p0, p1, p2, p3;
  p0.x = __uint_as_float(g.x << 16); p0.y = __uint_as_float(g.x & 0xFFFF0000u);
  p1.x = __uint_as_float(g.y << 16); p1.y = __uint_as_float(g.y & 0xFFFF0000u);
  p2.x = __uint_as_float(g.z << 16); p2.y = __uint_as_float(g.z & 0xFFFF0000u);
  p3.x = __uint_as_float(g.w << 16); p3.y = __uint_as_float(g.w & 0xFFFF0000u);
  pkfma(A01, p0, vv); pkfma(A23, p1, vv); pkfma(A45, p2, vv); pkfma(A67, p3, vv);
}

// ---------------------------------------------------------------------------
// CSR build (R4 full-line-write design, 1024-thread blocks — proven)
// ---------------------------------------------------------------------------
__global__ __launch_bounds__(1024) void p0_hist_k(const int* __restrict__ row,
                                                  int* __restrict__ h2d) {
  __shared__ int h[NBUK];
  const int i = blockIdx.x, t = threadIdx.x;
  if (t < NBUK) h[t] = 0;
  __syncthreads();
  const int e0 = i * EPP, e1 = e0 + EPP;
  for (int e = e0 + t; e < e1; e += 1024) atomicAdd(&h[row[e] / RPB], 1);
  __syncthreads();
  if (t < NBUK) h2d[i * NBUK + t] = h[t];  // coalesced
}

__global__ __launch_bounds__(256) void k1_scanb_k(int* __restrict__ h2d,
                                                  int* __restrict__ btot) {
  __shared__ int sd[256];
  const int b = blockIdx.x, t = threadIdx.x;
  int v = h2d[t * NBUK + b];
  sd[t] = v;
  __syncthreads();
  for (int off = 1; off < 256; off <<= 1) {
    int a = (t >= off) ? sd[t - off] : 0;
    __syncthreads();
    sd[t] += a;
    __syncthreads();
  }
  h2d[t * NBUK + b] = sd[t] - v;  // exclusive prefix within bucket
  if (t == 255) btot[b] = sd[255];
}

__global__ __launch_bounds__(256) void k2_scanbase_k(const int* __restrict__ btot,
                                                     int* __restrict__ bbase,
                                                     int2* __restrict__ ep) {
  __shared__ int sd[256];
  const int t = threadIdx.x;
  int v = btot[t];
  sd[t] = v;
  __syncthreads();
  for (int off = 1; off < 256; off <<= 1) {
    int a = (t >= off) ? sd[t - off] : 0;
    __syncthreads();
    sd[t] += a;
    __syncthreads();
  }
  bbase[t] = sd[t] - v;
  if (t == 255) bbase[256] = sd[255];  // == N_EDGES
  if (t < EP_PAD) ep[N_EDGES + t] = make_int2(0, 0);
}

__global__ __launch_bounds__(1024) void p2_part_k(
    const int* __restrict__ row, const int* __restrict__ col,
    const float* __restrict__ val, const int* __restrict__ h2d,
    const int* __restrict__ bbase, int2* __restrict__ pcv,
    unsigned short* __restrict__ plr) {
  __shared__ int cur[NBUK];
  const int i = blockIdx.x, t = threadIdx.x;
  if (t < NBUK) cur[t] = bbase[t] + h2d[i * NBUK + t];
  __syncthreads();
  const int e0 = i * EPP, e1 = e0 + EPP;
  for (int e = e0 + t; e < e1; e += 1024) {
    int r = row[e];
    int b = r / RPB;
    int p = atomicAdd(&cur[b], 1);
    pcv[p] = make_int2(col[e], __float_as_int(val[e]));
    plr[p] = (unsigned short)(r - b * RPB);
  }
}

__global__ __launch_bounds__(1024) void p3_fine_k(const int2* __restrict__ pcv,
                                                  const unsigned short* __restrict__ plr,
                                                  const int* __restrict__ bbase,
                                                  int* __restrict__ rp,
                                                  int2* __restrict__ ep) {
  __shared__ int cnt[RPB];
  __shared__ int cur[RPB];
  const int b = blockIdx.x, t = threadIdx.x;
  const int ebeg = bbase[b], eend = bbase[b + 1];
  const int r0 = b * RPB;
  const int nloc = min(RPB, N_NODES - r0);

  for (int i = t; i < RPB; i += 1024) cnt[i] = 0;
  __syncthreads();
  for (int j = ebeg + t; j < eend; j += 1024) atomicAdd(&cnt[plr[j]], 1);
  __syncthreads();

  if (t < 64) {  // exclusive scan of cnt[0..390] by wave 0
    const int base_ = t * 7;
    int v[7], s = 0;
#pragma unroll
    for (int k = 0; k < 7; ++k) {
      int idx = base_ + k;
      v[k] = (idx < RPB) ? cnt[idx] : 0;
      s += v[k];
    }
    int incl = s;
#pragma unroll
    for (int off = 1; off < 64; off <<= 1) {
      int y = __shfl_up(incl, off);
      if (t >= off) incl += y;
    }
    int run = incl - s;
#pragma unroll
    for (int k = 0; k < 7; ++k) {
      int idx = base_ + k;
      if (idx < RPB) cnt[idx] = run;
      run += v[k];
    }
  }
  __syncthreads();

  for (int i = t; i < nloc; i += 1024) {
    rp[r0 + i] = ebeg + cnt[i];
    cur[i] = cnt[i];
  }
  if (b == 0 && t == 0) rp[N_NODES] = N_EDGES;
  __syncthreads();

  for (int j = ebeg + t; j < eend; j += 1024) {
    int lr = plr[j];
    int p = atomicAdd(&cur[lr], 1);
    ep[ebeg + p] = pcv[j];
  }
}

// ---------------------------------------------------------------------------
// MFMA GEMM layer-1: S[N,64](bf16) = x[N,128](fp32->bf16) @ W1[128,64].
// ---------------------------------------------------------------------------
__global__ __launch_bounds__(256) void gemm_l1(const float* __restrict__ X,
                                               const float* __restrict__ W,
                                               unsigned short* __restrict__ S) {
  const int lane = threadIdx.x & 63;
  const int quad = lane >> 4;
  const int m = lane & 15;

  short8 bf[4][4];
#pragma unroll
  for (int t = 0; t < 4; ++t)
#pragma unroll
    for (int h = 0; h < 4; ++h)
#pragma unroll
      for (int j = 0; j < 8; ++j)
        bf[t][h][j] = f2bs(W[(h * 32 + quad * 8 + j) * 64 + t * 16 + m]);

  const int wid = blockIdx.x * 4 + (threadIdx.x >> 6);
  for (int tile = wid; tile < NTILES; tile += gridDim.x * 4) {
    const int r0 = tile * 16;
    const float* xr = X + (size_t)(r0 + m) * 128;
    short8 af[4];
#pragma unroll
    for (int h = 0; h < 4; ++h) {
      const float* p = xr + h * 32 + quad * 8;
      float4 a = *(const float4*)p;
      float4 b = *(const float4*)(p + 4);
      af[h][0] = f2bs(a.x); af[h][1] = f2bs(a.y);
      af[h][2] = f2bs(a.z); af[h][3] = f2bs(a.w);
      af[h][4] = f2bs(b.x); af[h][5] = f2bs(b.y);
      af[h][6] = f2bs(b.z); af[h][7] = f2bs(b.w);
    }
#pragma unroll
    for (int t = 0; t < 4; ++t) {
      floatx4 acc = {0.0f, 0.0f, 0.0f, 0.0f};
#pragma unroll
      for (int h = 0; h < 4; ++h)
        acc = __builtin_amdgcn_mfma_f32_16x16x32_bf16(af[h], bf[t][h], acc, 0, 0, 0);
#pragma unroll
      for (int r = 0; r < 4; ++r)
        S[(size_t)(r0 + quad * 4 + r) * 64 + t * 16 + m] = (unsigned short)f2bs(acc[r]);
    }
  }
}

// MFMA GEMM mid/final: S[N,64](bf16) = Hb[N,64](bf16) @ W[64,COLS](fp32).
// COLS=40 zero-fills cols 40..63 (finite, aligned 128-B rows for the gather).
template <int COLS>
__global__ __launch_bounds__(256) void gemm_bf(const unsigned short* __restrict__ Hb,
                                               const float* __restrict__ W,
                                               unsigned short* __restrict__ S) {
  const int lane = threadIdx.x & 63;
  const int quad = lane >> 4;
  const int m = lane & 15;

  short8 bf[4][2];
#pragma unroll
  for (int t = 0; t < 4; ++t) {
    const int cc = t * 16 + m;
#pragma unroll
    for (int h = 0; h < 2; ++h)
#pragma unroll
      for (int j = 0; j < 8; ++j)
        bf[t][h][j] = (COLS == 64 || cc < COLS)
                          ? f2bs(W[(h * 32 + quad * 8 + j) * COLS + cc])
                          : (short)0;
  }

  const int wid = blockIdx.x * 4 + (threadIdx.x >> 6);
  for (int tile = wid; tile < NTILES; tile += gridDim.x * 4) {
    const int r0 = tile * 16;
    const unsigned short* hr = Hb + (size_t)(r0 + m) * 64 + quad * 8;
    short8 af0 = *(const short8*)hr;
    short8 af1 = *(const short8*)(hr + 32);
#pragma unroll
    for (int t = 0; t < 4; ++t) {
      floatx4 acc = {0.0f, 0.0f, 0.0f, 0.0f};
      acc = __builtin_amdgcn_mfma_f32_16x16x32_bf16(af0, bf[t][0], acc, 0, 0, 0);
      acc = __builtin_amdgcn_mfma_f32_16x16x32_bf16(af1, bf[t][1], acc, 0, 0, 0);
#pragma unroll
      for (int r = 0; r < 4; ++r)
        S[(size_t)(r0 + quad * 4 + r) * 64 + t * 16 + m] = (unsigned short)f2bs(acc[r]);
    }
  }
}

// ---------------------------------------------------------------------------
// SpMM, 8-lanes-per-row geometry. R11: zero-rotation-mov pipeline — each trip
// processes 2 iterations and refills the SAME registers after consuming them
// (consume FMA -> re-gather -> re-extract guards -> re-load ep). Same 1-trip
// prefetch slack as the 492us baseline, but no shift-register movs. FMAs use
// v_pk_fma_f32 (IEEE per-half, bit-identical to scalar fmaf chains; per-a[j]
// contribution order unchanged).
// ---------------------------------------------------------------------------
template <bool RES>
__global__ __launch_bounds__(256) void spmm8_k(
    const unsigned short* __restrict__ S, const int2* __restrict__ ep,
    const int* __restrict__ rp, const float* __restrict__ bias,
    unsigned short* __restrict__ Hbout) {  // Hbout doubles as residual source
  const int lane = threadIdx.x & 63;
  const int og = lane >> 3;
  const int i8 = lane & 7;
  const int sg = og & 3;
  const bool isB = og >= 4;
  const int pair = blockIdx.x * 4 + (threadIdx.x >> 6);
  const int nodeA = pair * 2;
  const int sA = rp[nodeA], sB = rp[nodeA + 1], eB = rp[nodeA + 2];
  const int myNode = nodeA + (isB ? 1 : 0);
  const int myBeg = isB ? sB : sA;
  const int myEnd = isB ? eB : sB;
  const int iters = (max(sB - sA, eB - sB) + 7) >> 3;
  const int trips = (iters + 1) >> 1;

  const int base = myBeg + sg;
  const int2* epp = ep + base;
  const unsigned short* Sl = S + i8 * 8;

  float2v A01 = {0, 0}, A23 = {0, 0}, A45 = {0, 0}, A67 = {0, 0};

  // Prologue: ep for iters 0..3; gathers + guards for iters 0,1.
  int2 e0a = epp[0],  e0b = epp[4],  e1a = epp[8],  e1b = epp[12];
  int2 e2a = epp[16], e2b = epp[20], e3a = epp[24], e3b = epp[28];
  uint4 g0a = *(const uint4*)(Sl + (size_t)e0a.x * 64);
  uint4 g0b = *(const uint4*)(Sl + (size_t)e0b.x * 64);
  uint4 g1a = *(const uint4*)(Sl + (size_t)e1a.x * 64);
  uint4 g1b = *(const uint4*)(Sl + (size_t)e1b.x * 64);
  float v0a = (base      < myEnd) ? __int_as_float(e0a.y) : 0.0f;
  float v0b = (base + 4  < myEnd) ? __int_as_float(e0b.y) : 0.0f;
  float v1a = (base + 8  < myEnd) ? __int_as_float(e1a.y) : 0.0f;
  float v1b = (base + 12 < myEnd) ? __int_as_float(e1b.y) : 0.0f;

  int sl = base;
  for (int T = 0; T < trips; ++T) {
    // consume iters 2T, 2T+1 (gathers/guards issued one trip ago)
    fma8pk(A01, A23, A45, A67, v0a, g0a);
    fma8pk(A01, A23, A45, A67, v0b, g0b);
    fma8pk(A01, A23, A45, A67, v1a, g1a);
    fma8pk(A01, A23, A45, A67, v1b, g1b);
    // refill gathers + guards for iters 2T+2, 2T+3 from held ep
    g0a = *(const uint4*)(Sl + (size_t)e2a.x * 64);
    g0b = *(const uint4*)(Sl + (size_t)e2b.x * 64);
    g1a = *(const uint4*)(Sl + (size_t)e3a.x * 64);
    g1b = *(const uint4*)(Sl + (size_t)e3b.x * 64);
    v0a = (sl + 16 < myEnd) ? __int_as_float(e2a.y) : 0.0f;
    v0b = (sl + 20 < myEnd) ? __int_as_float(e2b.y) : 0.0f;
    v1a = (sl + 24 < myEnd) ? __int_as_float(e3a.y) : 0.0f;
    v1b = (sl + 28 < myEnd) ? __int_as_float(e3b.y) : 0.0f;
    // re-load ep for iters 2T+4, 2T+5 (EP_PAD covers overrun)
    e2a = epp[32]; e2b = epp[36]; e3a = epp[40]; e3b = epp[44];
    epp += 16; sl += 16;
  }

  float a0 = A01.x, a1 = A01.y, a2 = A23.x, a3 = A23.y;
  float a4 = A45.x, a5 = A45.y, a6 = A67.x, a7 = A67.y;
  a0 += __shfl_xor(a0, 8); a0 += __shfl_xor(a0, 16);
  a1 += __shfl_xor(a1, 8); a1 += __shfl_xor(a1, 16);
  a2 += __shfl_xor(a2, 8); a2 += __shfl_xor(a2, 16);
  a3 += __shfl_xor(a3, 8); a3 += __shfl_xor(a3, 16);
  a4 += __shfl_xor(a4, 8); a4 += __shfl_xor(a4, 16);
  a5 += __shfl_xor(a5, 8); a5 += __shfl_xor(a5, 16);
  a6 += __shfl_xor(a6, 8); a6 += __shfl_xor(a6, 16);
  a7 += __shfl_xor(a7, 8); a7 += __shfl_xor(a7, 16);

  if (sg == 0) {  // og==0 (node A) / og==4 (node B): lane holds feats i8*8..+7
    float4 b0 = ((const float4*)bias)[i8 * 2];
    float4 b1 = ((const float4*)bias)[i8 * 2 + 1];
    float h[8];
    h[0] = fmaxf(a0 + b0.x, 0.0f); h[1] = fmaxf(a1 + b0.y, 0.0f);
    h[2] = fmaxf(a2 + b0.z, 0.0f); h[3] = fmaxf(a3 + b0.w, 0.0f);
    h[4] = fmaxf(a4 + b1.x, 0.0f); h[5] = fmaxf(a5 + b1.y, 0.0f);
    h[6] = fmaxf(a6 + b1.z, 0.0f); h[7] = fmaxf(a7 + b1.w, 0.0f);
    if (RES) {
      ushort8v r = ((const ushort8v*)Hbout)[(size_t)myNode * 8 + i8];
#pragma unroll
      for (int j = 0; j < 8; ++j) h[j] += bfbits(r[j]);
    }
    ushort8v hb;
#pragma unroll
    for (int j = 0; j < 8; ++j) hb[j] = (unsigned short)f2bs(h[j]);
    ((ushort8v*)Hbout)[(size_t)myNode * 8 + i8] = hb;
  }
}

// Final: same zero-mov pipelined gather on stride-64 S (cols 40..63 zero) +
// bias + log_softmax.
__global__ __launch_bounds__(256) void spmm_final_k(
    const unsigned short* __restrict__ S, const int2* __restrict__ ep,
    const int* __restrict__ rp, const float* __restrict__ b2,
    float* __restrict__ out) {
  const int lane = threadIdx.x & 63;
  const int og = lane >> 3;
  const int i8 = lane & 7;
  const int sg = og & 3;
  const bool isB = og >= 4;
  const int pair = blockIdx.x * 4 + (threadIdx.x >> 6);
  const int nodeA = pair * 2;
  const int sA = rp[nodeA], sB = rp[nodeA + 1], eB = rp[nodeA + 2];
  const int myNode = nodeA + (isB ? 1 : 0);
  const int myBeg = isB ? sB : sA;
  const int myEnd = isB ? eB : sB;
  const int iters = (max(sB - sA, eB - sB) + 7) >> 3;
  const int trips = (iters + 1) >> 1;

  const int base = myBeg + sg;
  const int2* epp = ep + base;
  const unsigned short* Sl = S + i8 * 8;

  float2v A01 = {0, 0}, A23 = {0, 0}, A45 = {0, 0}, A67 = {0, 0};

  int2 e0a = epp[0],  e0b = epp[4],  e1a = epp[8],  e1b = epp[12];
  int2 e2a = epp[16], e2b = epp[20], e3a = epp[24], e3b = epp[28];
  uint4 g0a = *(const uint4*)(Sl + (size_t)e0a.x * 64);
  uint4 g0b = *(const uint4*)(Sl + (size_t)e0b.x * 64);
  uint4 g1a = *(const uint4*)(Sl + (size_t)e1a.x * 64);
  uint4 g1b = *(const uint4*)(Sl + (size_t)e1b.x * 64);
  float v0a = (base      < myEnd) ? __int_as_float(e0a.y) : 0.0f;
  float v0b = (base + 4  < myEnd) ? __int_as_float(e0b.y) : 0.0f;
  float v1a = (base + 8  < myEnd) ? __int_as_float(e1a.y) : 0.0f;
  float v1b = (base + 12 < myEnd) ? __int_as_float(e1b.y) : 0.0f;

  int sl = base;
  for (int T = 0; T < trips; ++T) {
    fma8pk(A01, A23, A45, A67, v0a, g0a);
    fma8pk(A01, A23, A45, A67, v0b, g0b);
    fma8pk(A01, A23, A45, A67, v1a, g1a);
    fma8pk(A01, A23, A45, A67, v1b, g1b);
    g0a = *(const uint4*)(Sl + (size_t)e2a.x * 64);
    g0b = *(const uint4*)(Sl + (size_t)e2b.x * 64);
    g1a = *(const uint4*)(Sl + (size_t)e3a.x * 64);
    g1b = *(const uint4*)(Sl + (size_t)e3b.x * 64);
    v0a = (sl + 16 < myEnd) ? __int_as_float(e2a.y) : 0.0f;
    v0b = (sl + 20 < myEnd) ? __int_as_float(e2b.y) : 0.0f;
    v1a = (sl + 24 < myEnd) ? __int_as_float(e3a.y) : 0.0f;
    v1b = (sl + 28 < myEnd) ? __int_as_float(e3b.y) : 0.0f;
    e2a = epp[32]; e2b = epp[36]; e3a = epp[40]; e3b = epp[44];
    epp += 16; sl += 16;
  }

  float a0 = A01.x, a1 = A01.y, a2 = A23.x, a3 = A23.y;
  float a4 = A45.x, a5 = A45.y, a6 = A67.x, a7 = A67.y;
  a0 += __shfl_xor(a0, 8); a0 += __shfl_xor(a0, 16);
  a1 += __shfl_xor(a1, 8); a1 += __shfl_xor(a1, 16);
  a2 += __shfl_xor(a2, 8); a2 += __shfl_xor(a2, 16);
  a3 += __shfl_xor(a3, 8); a3 += __shfl_xor(a3, 16);
  a4 += __shfl_xor(a4, 8); a4 += __shfl_xor(a4, 16);
  a5 += __shfl_xor(a5, 8); a5 += __shfl_xor(a5, 16);
  a6 += __shfl_xor(a6, 8); a6 += __shfl_xor(a6, 16);
  a7 += __shfl_xor(a7, 8); a7 += __shfl_xor(a7, 16);

  // lane i8 holds feats i8*8..+7; valid class lanes: i8 < 5 (5*8 = 40)
  const bool valid = (i8 < 5);
  float l[8];
  float mx = -INFINITY;
  if (valid) {
    float4 c0 = ((const float4*)b2)[i8 * 2];
    float4 c1 = ((const float4*)b2)[i8 * 2 + 1];
    l[0] = a0 + c0.x; l[1] = a1 + c0.y; l[2] = a2 + c0.z; l[3] = a3 + c0.w;
    l[4] = a4 + c1.x; l[5] = a5 + c1.y; l[6] = a6 + c1.z; l[7] = a7 + c1.w;
#pragma unroll
    for (int j = 0; j < 8; ++j) mx = fmaxf(mx, l[j]);
  }
#pragma unroll
  for (int off = 1; off < 8; off <<= 1) mx = fmaxf(mx, __shfl_xor(mx, off));
  float sum = 0.0f;
  if (valid) {
#pragma unroll
    for (int j = 0; j < 8; ++j) sum += expf(l[j] - mx);
  }
#pragma unroll
  for (int off = 1; off < 8; off <<= 1) sum += __shfl_xor(sum, off);

  if (sg == 0 && valid) {
    float lg = mx + logf(sum);
    ((float4*)out)[(size_t)myNode * 10 + i8 * 2] =
        make_float4(l[0] - lg, l[1] - lg, l[2] - lg, l[3] - lg);
    ((float4*)out)[(size_t)myNode * 10 + i8 * 2 + 1] =
        make_float4(l[4] - lg, l[5] - lg, l[6] - lg, l[7] - lg);
  }
}

// ---------------------------------------------------------------------------
extern "C" void kernel_launch(void* const* d_in, const int* in_sizes, int n_in,
                              void* d_out, int out_size, void* d_ws, size_t ws_size,
                              hipStream_t stream) {
  const float* x    = (const float*)d_in[0];
  const int*   erow = (const int*)d_in[1];
  const int*   ecol = (const int*)d_in[2];
  const float* eval = (const float*)d_in[3];
  const float* W1   = (const float*)d_in[4];
  const float* b1   = (const float*)d_in[5];
  const float* Wm   = (const float*)d_in[6];
  const float* bm   = (const float*)d_in[7];
  const float* W2   = (const float*)d_in[8];
  const float* b2   = (const float*)d_in[9];
  float* out = (float*)d_out;

  // Workspace (~55 MB). pcv/plr dead after p3_fine_k -> S aliases them.
  char* ws = (char*)d_ws;
  size_t off = 0;
  auto alloc = [&](size_t bytes) {
    void* p = ws + off;
    off = (off + bytes + 255) & ~(size_t)255;
    return p;
  };
  int*  rp    = (int*)alloc((N_NODES + 1) * sizeof(int));
  int*  h2d   = (int*)alloc((size_t)NBUK * NBUK * sizeof(int));
  int*  btot  = (int*)alloc(NBUK * sizeof(int));
  int*  bbase = (int*)alloc((NBUK + 1) * sizeof(int));
  int2* ep    = (int2*)alloc((size_t)(N_EDGES + EP_PAD) * sizeof(int2));
  char* U     = (char*)alloc((size_t)N_EDGES * sizeof(int2) +
                             (((size_t)N_EDGES * sizeof(unsigned short) + 255) & ~(size_t)255));
  int2* pcv = (int2*)U;
  unsigned short* plr = (unsigned short*)(U + (size_t)N_EDGES * sizeof(int2));
  unsigned short* S = (unsigned short*)U;  // alias: live only after CSR build
  unsigned short* B0 = (unsigned short*)alloc((size_t)N_NODES * 64 * sizeof(unsigned short));
  unsigned short* B1 = (unsigned short*)alloc((size_t)N_NODES * 64 * sizeof(unsigned short));

  const int SPMM_GRID = N_NODES / 8;  // 12500 blocks x 4 waves x 2 nodes
  const int GEMM_GRID = 512;          // persistent: 2048 waves, ~3 tiles each

  // CSR build
  p0_hist_k<<<NBUK, 1024, 0, stream>>>(erow, h2d);
  k1_scanb_k<<<NBUK, 256, 0, stream>>>(h2d, btot);
  k2_scanbase_k<<<1, 256, 0, stream>>>(btot, bbase, ep);
  p2_part_k<<<NBUK, 1024, 0, stream>>>(erow, ecol, eval, h2d, bbase, pcv, plr);
  p3_fine_k<<<NBUK, 1024, 0, stream>>>(pcv, plr, bbase, rp, ep);

  // L1: S = x@W1 ; h1 = relu(A S + b1) -> B0
  gemm_l1<<<GEMM_GRID, 256, 0, stream>>>(x, W1, S);
  spmm8_k<false><<<SPMM_GRID, 256, 0, stream>>>(S, ep, rp, b1, B0);

  // L2: S = h1@Wm0 ; h2 -> B1
  gemm_bf<64><<<GEMM_GRID, 256, 0, stream>>>(B0, Wm, S);
  spmm8_k<false><<<SPMM_GRID, 256, 0, stream>>>(S, ep, rp, bm, B1);

  // L3: h3 = relu(A (h2@Wm1) + bm1) + h1(B0) -> B0
  gemm_bf<64><<<GEMM_GRID, 256, 0, stream>>>(B1, Wm + 1 * 4096, S);
  spmm8_k<true><<<SPMM_GRID, 256, 0, stream>>>(S, ep, rp, bm + 1 * 64, B0);

  // L4: h4 = ... + h2(B1) -> B1
  gemm_bf<64><<<GEMM_GRID, 256, 0, stream>>>(B0, Wm + 2 * 4096, S);
  spmm8_k<true><<<SPMM_GRID, 256, 0, stream>>>(S, ep, rp, bm + 2 * 64, B1);

  // L5: h5 = ... + h3(B0) -> B0
  gemm_bf<64><<<GEMM_GRID, 256, 0, stream>>>(B1, Wm + 3 * 4096, S);
  spmm8_k<true><<<SPMM_GRID, 256, 0, stream>>>(S, ep, rp, bm + 3 * 64, B0);

  // L6: h6 = ... + h4(B1) -> B1
  gemm_bf<64><<<GEMM_GRID, 256, 0, stream>>>(B0, Wm + 4 * 4096, S);
  spmm8_k<true><<<SPMM_GRID, 256, 0, stream>>>(S, ep, rp, bm + 4 * 64, B1);

  // L7: h7 = ... + h5(B0) -> B0
  gemm_bf<64><<<GEMM_GRID, 256, 0, stream>>>(B1, Wm + 5 * 4096, S);
  spmm8_k<true><<<SPMM_GRID, 256, 0, stream>>>(S, ep, rp, bm + 5 * 64, B0);

  // Final: S (stride 64, cols 40..63 zero) = h7@W2 ; out = log_softmax(A S + b2)
  gemm_bf<40><<<GEMM_GRID, 256, 0, stream>>>(B0, W2, S);
  spmm_final_k<<<SPMM_GRID, 256, 0, stream>>>(S, ep, rp, b2, out);
}